// Round 4
// baseline (29.413 us; speedup 1.0000x reference)
//
#include <hip/hip_runtime.h>

// Scalar VQ (dim=1, K=64) via per-block bucket LUT (depth-1 LDS chain).
// key(x) = clamp(floor((x-lo)*inv), 0, NB-1) is fl-monotone; the build uses
// the SAME key function on the codes, so for any w with key(w)=k:
//   pos(w) = #{c <= w} = p0(k) + (S[p0+1]<=w) + (S[p0+2]<=w)
// exactly, whenever bucket k holds <=2 codes (codes in later buckets compare
// false automatically by monotonicity). Buckets with >=3 codes are marked NaN
// and handled (with exact fl-ties between distinct values) by the verbatim
// naive reference scan under a __any guard. Candidates compared with exact
// reference arithmetic: d=fl(w-c), d2=fl(d*d); +inf sentinels kill ends.

#define VQ_K 64
#define NB   2048
#define TPB  256
#define SEG  8
#define BLK_F4 (TPB * SEG)   // 2048 float4 (8192 floats) per block

__device__ __forceinline__ int vq_key(float x, float lo, float inv) {
    float t = (x - lo) * inv;
    t = fminf(fmaxf(t, 0.0f), (float)(NB - 1));
    return (int)t;
}

__global__ __launch_bounds__(TPB) void vq_kernel(
    const float* __restrict__ w,
    const float* __restrict__ cb,
    float* __restrict__ out,
    int n4)                    // number of float4 groups
{
    __shared__ float  C[VQ_K];        // original-order codebook (fallback)
    __shared__ float  S[VQ_K + 4];    // [0]=+inf, [1..64] sorted, [65..67]=+inf
    __shared__ float4 T[NB];          // bucket entries (a,b,c,d)
    __shared__ unsigned int H[NB / 4];// byte-packed per-bucket code counts
    __shared__ int    P[TPB];         // scan partials
    __shared__ int    Q[TPB / 64];    // per-wave totals

    const int tid = threadIdx.x;
    const float INF = __builtin_inff();

    if (tid < VQ_K) C[tid] = cb[tid];
    H[2 * tid]     = 0u;
    H[2 * tid + 1] = 0u;
    __syncthreads();

    // Stable rank-sort into S[1..64].
    if (tid < VQ_K) {
        const float c = C[tid];
        int rank = 0;
#pragma unroll
        for (int j = 0; j < VQ_K; ++j) {
            const float cj = C[j];
            rank += (cj < c || (cj == c && j < tid)) ? 1 : 0;
        }
        S[rank + 1] = c;
    }
    if (tid == 0) S[0] = INF;
    if (tid >= 1 && tid <= 3) S[VQ_K + tid] = INF;
    __syncthreads();

    const float lo  = S[1];
    const float hi  = S[VQ_K];
    const float inv = (hi > lo) ? ((float)NB / (hi - lo)) : 0.0f;

    // Histogram of code keys (byte-packed; counts <= 64 so no overflow).
    if (tid < VQ_K) {
        const int k = vq_key(S[tid + 1], lo, inv);
        atomicAdd(&H[k >> 2], 1u << ((k & 3) * 8));
    }
    __syncthreads();

    // Each thread owns buckets 8t..8t+7: local counts + exclusive prefix.
    const unsigned int h01 = H[2 * tid], h23 = H[2 * tid + 1];
    int h[8], e[8];
    {
        int run = 0;
#pragma unroll
        for (int j = 0; j < 8; ++j) {
            const unsigned int word = (j < 4) ? h01 : h23;
            h[j] = (int)((word >> ((j & 3) * 8)) & 0xFFu);
            e[j] = run;
            run += h[j];
        }
        P[tid] = run;
    }
    __syncthreads();

    // Block-wide exclusive scan of P (wave scan + wave offsets).
    int val = P[tid];
    const int lane = tid & 63;
#pragma unroll
    for (int d = 1; d < 64; d <<= 1) {
        int u = __shfl_up(val, d, 64);
        if (lane >= d) val += u;
    }
    if (lane == 63) Q[tid >> 6] = val;
    __syncthreads();
    int base = val - P[tid];
    {
        const int wid = tid >> 6;
        for (int i = 0; i < wid; ++i) base += Q[i];
    }

    // Write bucket entries.
    const float NANF = __uint_as_float(0x7fc00000u);
#pragma unroll
    for (int j = 0; j < 8; ++j) {
        const int k  = tid * 8 + j;
        const int p0 = base + e[j];               // in [0,64]; p0+3 <= 67
        float4 ent;
        if (h[j] >= 3) {
            ent = make_float4(NANF, NANF, NANF, NANF);
        } else {
            ent = make_float4(S[p0], S[p0 + 1], S[p0 + 2], S[p0 + 3]);
        }
        T[k] = ent;
    }
    __syncthreads();

    // ---- stream elements ----
    const int base4 = blockIdx.x * BLK_F4 + tid;
    float4 x[SEG];
    bool   ok[SEG];
#pragma unroll
    for (int s = 0; s < SEG; ++s) {
        const int i4 = base4 + s * TPB;
        ok[s] = (i4 < n4);
        if (ok[s]) x[s] = reinterpret_cast<const float4*>(w)[i4];
    }

#pragma unroll
    for (int s = 0; s < SEG; ++s) {
        if (!ok[s]) continue;
        float ex[4] = {x[s].x, x[s].y, x[s].z, x[s].w};
        float r[4];
#pragma unroll
        for (int j = 0; j < 4; ++j) {
            const float wv = ex[j];
            const int k = vq_key(wv, lo, inv);
            const float4 ent = T[k];              // one ds_read_b128
            const bool s1 = (ent.y <= wv);
            const bool s2 = (ent.z <= wv);
            const float cl = s2 ? ent.z : (s1 ? ent.y : ent.x);
            const float cr = s2 ? ent.w : (s1 ? ent.z : ent.y);
            const float dl = wv - cl, dr = wv - cr;
            const float dl2 = dl * dl, dr2 = dr * dr;
            float q = (dr2 < dl2) ? cr : cl;
            const bool bad = (q != q) || (dl2 == dr2 && cl != cr);
            if (__any(bad)) {                     // uniform, ~never taken
                if (bad) {
                    float c0 = C[0];
                    float d0 = wv - c0;
                    float bd = d0 * d0, bv = c0;
#pragma unroll 1
                    for (int kk = 1; kk < VQ_K; ++kk) {
                        float c = C[kk], d = wv - c, dd = d * d;
                        bool lt = dd < bd;
                        bd = lt ? dd : bd;
                        bv = lt ? c : bv;
                    }
                    q = bv;
                }
            }
            r[j] = q;
        }
        reinterpret_cast<float4*>(out)[base4 + s * TPB] =
            make_float4(r[0], r[1], r[2], r[3]);
    }
}

// Naive exact fallback for tail elements (n % 4 != 0).
__global__ void vq_tail_kernel(const float* __restrict__ w,
                               const float* __restrict__ cb,
                               float* __restrict__ out, int start, int n) {
    int i = start + blockIdx.x * blockDim.x + threadIdx.x;
    if (i >= n) return;
    float wx = w[i];
    float c0 = cb[0], d0 = wx - c0;
    float bd = d0 * d0, bv = c0;
#pragma unroll
    for (int k = 1; k < VQ_K; ++k) {
        float c = cb[k], d = wx - c, dd = d * d;
        bool lt = dd < bd;
        bd = lt ? dd : bd;
        bv = lt ? c : bv;
    }
    out[i] = bv;
}

extern "C" void kernel_launch(void* const* d_in, const int* in_sizes, int n_in,
                              void* d_out, int out_size, void* d_ws, size_t ws_size,
                              hipStream_t stream) {
    const float* w  = (const float*)d_in[0];
    const float* cb = (const float*)d_in[1];
    float* out = (float*)d_out;
    const int n  = in_sizes[0];
    const int n4 = n / 4;

    if (n4 > 0) {
        const int grid = (n4 + BLK_F4 - 1) / BLK_F4;
        vq_kernel<<<grid, TPB, 0, stream>>>(w, cb, out, n4);
    }
    if (n4 * 4 < n) {
        vq_tail_kernel<<<1, 64, 0, stream>>>(w, cb, out, n4 * 4, n);
    }
}

// Round 5
// 25.247 us; speedup vs baseline: 1.1650x; 1.1650x over previous
//
#include <hip/hip_runtime.h>

// Scalar VQ (dim=1, K=64) via per-block bucket LUT, depth-1 LDS chain.
// key(x)=clamp((x-lo)*inv,0,NB-1) is fl-monotone; build uses the SAME key on
// the sorted codes, so for key(w)=k with <=2 codes in bucket k:
//   pos(w) = #{c<=w} = p0(k) + (S[p0+1]<=w) + (S[p0+2]<=w)   (exact)
// Candidates S[pos],S[pos+1] compared with exact reference arithmetic
// (d=fl(w-c), d2=fl(d*d)); >=3-code buckets are NaN-marked; those, exact
// fl-ties between distinct values, and non-finite w fall back to the verbatim
// naive first-index scan under a __any guard (~never taken).

#define VQ_K 64
#define NB   1024
#define NW   (NB / 4)          // byte-packed histogram words (== TPB)
#define TPB  256
#define SEG  4
#define BLK_F4 (TPB * SEG)     // 1024 float4 = 4096 floats per block

__device__ __forceinline__ int vq_key(float x, float lo, float inv) {
    float t = (x - lo) * inv;
    t = fminf(fmaxf(t, 0.0f), (float)(NB - 1));
    return (int)t;
}

__device__ __forceinline__ unsigned bytesum(unsigned x) {
    return (x + (x >> 8) + (x >> 16) + (x >> 24)) & 0xFFu;
}

__global__ __launch_bounds__(TPB) void vq_kernel(
    const float* __restrict__ w,
    const float* __restrict__ cb,
    float* __restrict__ out,
    int n4)
{
    __shared__ float  C[VQ_K];        // original order (fallback)
    __shared__ float  S[VQ_K + 4];    // [0]=inf, [1..64] sorted, [65..67]=inf
    __shared__ float4 T[NB];          // 16 KB bucket table
    __shared__ unsigned H[NW];        // byte-packed counts
    __shared__ unsigned Hs[NW];       // word-exclusive code prefix

    const int tid = threadIdx.x;
    const float INF = __builtin_inff();
    const float NANF = __uint_as_float(0x7fc00000u);

    if (tid < VQ_K) C[tid] = cb[tid];
    H[tid] = 0u;                       // NW == TPB
    __syncthreads();

    // Stable rank-sort into S[1..64].
    if (tid < VQ_K) {
        const float c = C[tid];
        int rank = 0;
#pragma unroll
        for (int j = 0; j < VQ_K; ++j) {
            const float cj = C[j];
            rank += (cj < c || (cj == c && j < tid)) ? 1 : 0;
        }
        S[rank + 1] = c;
    }
    if (tid == 0) S[0] = INF;
    if (tid >= VQ_K + 1 && tid <= VQ_K + 3) S[tid] = INF;
    __syncthreads();

    const float lo  = S[1];
    const float hi  = S[VQ_K];
    const float inv = (hi > lo) ? ((float)NB / (hi - lo)) : 0.0f;

    if (tid < VQ_K) {
        const int k = vq_key(S[tid + 1], lo, inv);
        atomicAdd(&H[k >> 2], 1u << ((k & 3) * 8));
    }
    __syncthreads();

    // Wave 0: exclusive scan over 256 words (4 words/lane + shfl scan).
    if (tid < 64) {
        const unsigned w0 = H[4 * tid], w1 = H[4 * tid + 1];
        const unsigned w2 = H[4 * tid + 2], w3 = H[4 * tid + 3];
        const int s0 = (int)bytesum(w0), s1 = (int)bytesum(w1);
        const int s2 = (int)bytesum(w2), s3 = (int)bytesum(w3);
        const int tot = s0 + s1 + s2 + s3;
        int acc = tot;
#pragma unroll
        for (int d = 1; d < 64; d <<= 1) {
            int u = __shfl_up(acc, d, 64);
            if ((tid & 63) >= d) acc += u;
        }
        const int base = acc - tot;
        Hs[4 * tid]     = (unsigned)base;
        Hs[4 * tid + 1] = (unsigned)(base + s0);
        Hs[4 * tid + 2] = (unsigned)(base + s0 + s1);
        Hs[4 * tid + 3] = (unsigned)(base + s0 + s1 + s2);
    }
    __syncthreads();

    // Fill T: thread t owns buckets {t, 256+t, 512+t, 768+t} -> lane-consecutive
    // 16B writes (conflict-free b128).
#pragma unroll
    for (int j = 0; j < 4; ++j) {
        const int b = tid + j * TPB;
        const unsigned hw = H[b >> 2];
        const int sh = (b & 3) * 8;
        const int h = (int)((hw >> sh) & 0xFFu);
        const unsigned below = hw & ((sh == 0) ? 0u : ((1u << sh) - 1u));
        const int p0 = (int)Hs[b >> 2] + (int)bytesum(below);
        float4 ent;
        if (h >= 3) ent = make_float4(NANF, NANF, NANF, NANF);
        else        ent = make_float4(S[p0], S[p0 + 1], S[p0 + 2], S[p0 + 3]);
        T[b] = ent;
    }
    __syncthreads();

    // ---- stream 4096 elements per block ----
    const int base4 = blockIdx.x * BLK_F4 + tid;   // full blocks only
    const float4* in4 = reinterpret_cast<const float4*>(w);
    float4* out4 = reinterpret_cast<float4*>(out);

    float4 x[SEG];
#pragma unroll
    for (int s = 0; s < SEG; ++s) x[s] = in4[base4 + s * TPB];

#pragma unroll
    for (int s = 0; s < SEG; ++s) {
        float ex[4] = {x[s].x, x[s].y, x[s].z, x[s].w};
        float r[4];
#pragma unroll
        for (int j = 0; j < 4; ++j) {
            const float wv = ex[j];
            const int k = vq_key(wv, lo, inv);
            const float4 ent = T[k];              // one ds_read_b128
            const bool s1 = (ent.y <= wv);
            const bool s2 = (ent.z <= wv);
            const float cl = s2 ? ent.z : (s1 ? ent.y : ent.x);
            const float cr = s2 ? ent.w : (s1 ? ent.z : ent.y);
            const float dl = wv - cl, dr = wv - cr;
            const float dl2 = dl * dl, dr2 = dr * dr;
            float q = (dr2 < dl2) ? cr : cl;
            const bool bad = (q != q) || (dl2 == dr2 && cl != cr)
                             || !((wv - wv) == 0.0f);
            if (__any(bad)) {                     // uniform, ~never taken
                if (bad) {
                    float c0 = C[0], d0 = wv - c0;
                    float bd = d0 * d0, bv = c0;
#pragma unroll 1
                    for (int kk = 1; kk < VQ_K; ++kk) {
                        float c = C[kk], d = wv - c, dd = d * d;
                        bool lt = dd < bd;
                        bd = lt ? dd : bd;
                        bv = lt ? c : bv;
                    }
                    q = bv;
                }
            }
            r[j] = q;
        }
        out4[base4 + s * TPB] = make_float4(r[0], r[1], r[2], r[3]);
    }
}

// Naive exact fallback for any remainder elements.
__global__ void vq_tail_kernel(const float* __restrict__ w,
                               const float* __restrict__ cb,
                               float* __restrict__ out, int start, int n) {
    int i = start + blockIdx.x * blockDim.x + threadIdx.x;
    if (i >= n) return;
    float wx = w[i];
    float c0 = cb[0], d0 = wx - c0;
    float bd = d0 * d0, bv = c0;
#pragma unroll
    for (int k = 1; k < VQ_K; ++k) {
        float c = cb[k], d = wx - c, dd = d * d;
        bool lt = dd < bd;
        bd = lt ? dd : bd;
        bv = lt ? c : bv;
    }
    out[i] = bv;
}

extern "C" void kernel_launch(void* const* d_in, const int* in_sizes, int n_in,
                              void* d_out, int out_size, void* d_ws, size_t ws_size,
                              hipStream_t stream) {
    const float* w  = (const float*)d_in[0];
    const float* cb = (const float*)d_in[1];
    float* out = (float*)d_out;
    const int n  = in_sizes[0];
    const int n4 = n / 4;

    const int grid = n4 / BLK_F4;                 // full blocks only
    if (grid > 0) {
        vq_kernel<<<grid, TPB, 0, stream>>>(w, cb, out, n4);
    }
    const int done = grid * BLK_F4 * 4;
    if (done < n) {
        const int rem = n - done;
        vq_tail_kernel<<<(rem + TPB - 1) / TPB, TPB, 0, stream>>>(w, cb, out, done, n);
    }
}